// Round 1
// baseline (5155.142 us; speedup 1.0000x reference)
//
#include <hip/hip_runtime.h>
#include <math.h>

#define DEPTH 3
#define HEADS 8
#define DIM 512
#define NCLS 4
#define EPSV 1e-5f
#define BB 2
#define NN 2560
#define HD 64
#define NTOK 512            // tokens per modality block = N/(NCLS+1)
#define ATT_SCALE 0.125f    // hd^-0.5

// ---------------- LayerNorm: one wave (64 lanes) per row of 512 ----------------
__global__ __launch_bounds__(256) void ln_kernel(const float* __restrict__ x,
                                                 const float* __restrict__ g,
                                                 const float* __restrict__ b,
                                                 float* __restrict__ out) {
    int wave = threadIdx.x >> 6;
    int lane = threadIdx.x & 63;
    int row  = blockIdx.x * 4 + wave;          // grid.x = 5120/4
    const float* xr = x + (size_t)row * DIM;
    float v[8];
    float s = 0.f, ss = 0.f;
#pragma unroll
    for (int i = 0; i < 8; ++i) {
        v[i] = xr[lane + i * 64];
        s += v[i]; ss += v[i] * v[i];
    }
#pragma unroll
    for (int off = 32; off >= 1; off >>= 1) {
        s  += __shfl_xor(s,  off, 64);
        ss += __shfl_xor(ss, off, 64);
    }
    float mu   = s * (1.f / DIM);
    float var  = ss * (1.f / DIM) - mu * mu;
    float rstd = rsqrtf(var + EPSV);
    float* orow = out + (size_t)row * DIM;
#pragma unroll
    for (int i = 0; i < 8; ++i) {
        int c = lane + i * 64;
        orow[c] = (v[i] - mu) * rstd * g[c] + b[c];
    }
}

__device__ inline float gelu_tanh(float x) {
    float x3 = x * x * x;
    return 0.5f * x * (1.f + tanhf(0.7978845608028654f * (x + 0.044715f * x3)));
}

// ---------------- Generic tiled fp32 GEMM ----------------
// C[M,N] (+= if RESID) alpha * A[M,K] @ B[K,N or N,K if TRANSB] (+bias) (gelu)
// Batched over blockIdx.z decomposed as (b, h) with independent strides.
// Requires: M%64==0, N%64==0, K%16==0.
template <bool TRANSB, bool GELU, bool RESID>
__global__ __launch_bounds__(256) void gemm_kernel(
    const float* __restrict__ A, int lda, long long sAb, long long sAh,
    const float* __restrict__ B, int ldb, long long sBb, long long sBh,
    float* __restrict__ C, int ldc, long long sCb, long long sCh,
    int M, int N, int K, float alpha, const float* __restrict__ bias, int nh) {
    __shared__ float As[16][68];
    __shared__ float Bs[16][68];

    int bz = blockIdx.z / nh;
    int hz = blockIdx.z % nh;
    A += bz * sAb + hz * sAh;
    B += bz * sBb + hz * sBh;
    C += bz * sCb + hz * sCh;

    int tid = threadIdx.x;
    int tx = tid & 15;          // 0..15 -> n quad
    int ty = tid >> 4;          // 0..15 -> m quad
    int row0 = blockIdx.y * 64;
    int n0   = blockIdx.x * 64;

    float acc[4][4];
#pragma unroll
    for (int i = 0; i < 4; ++i)
#pragma unroll
        for (int j = 0; j < 4; ++j) acc[i][j] = 0.f;

    // A-tile load mapping: m = tid>>2 (0..63), kq = tid&3 (k quad)
    int am = tid >> 2, akq = tid & 3;

    for (int k0 = 0; k0 < K; k0 += 16) {
        // load A tile 64x16 (float4 along k)
        {
            const float4 a4 = *(const float4*)&A[(size_t)(row0 + am) * lda + k0 + akq * 4];
            As[akq * 4 + 0][am] = a4.x;
            As[akq * 4 + 1][am] = a4.y;
            As[akq * 4 + 2][am] = a4.z;
            As[akq * 4 + 3][am] = a4.w;
        }
        // load B tile 16x64
        if (TRANSB) {
            // B is [N,K]; Bs[kk][n] = B[n0+n][k0+kk]
            int bn = tid >> 2, bkq = tid & 3;
            const float4 b4 = *(const float4*)&B[(size_t)(n0 + bn) * ldb + k0 + bkq * 4];
            Bs[bkq * 4 + 0][bn] = b4.x;
            Bs[bkq * 4 + 1][bn] = b4.y;
            Bs[bkq * 4 + 2][bn] = b4.z;
            Bs[bkq * 4 + 3][bn] = b4.w;
        } else {
            // B is [K,N]; coalesced row loads
            int bkk = tid >> 4, bnq = tid & 15;
            const float4 b4 = *(const float4*)&B[(size_t)(k0 + bkk) * ldb + n0 + bnq * 4];
            *(float4*)&Bs[bkk][bnq * 4] = b4;
        }
        __syncthreads();
#pragma unroll
        for (int kk = 0; kk < 16; ++kk) {
            float4 a4 = *(const float4*)&As[kk][ty * 4];
            float4 b4 = *(const float4*)&Bs[kk][tx * 4];
            float a[4] = {a4.x, a4.y, a4.z, a4.w};
            float b[4] = {b4.x, b4.y, b4.z, b4.w};
#pragma unroll
            for (int i = 0; i < 4; ++i)
#pragma unroll
                for (int j = 0; j < 4; ++j) acc[i][j] += a[i] * b[j];
        }
        __syncthreads();
    }

    // epilogue
    int col = n0 + tx * 4;
    float4 bv = make_float4(0.f, 0.f, 0.f, 0.f);
    if (bias) bv = *(const float4*)&bias[col];
#pragma unroll
    for (int i = 0; i < 4; ++i) {
        int row = row0 + ty * 4 + i;
        float4* cp = (float4*)&C[(size_t)row * ldc + col];
        float r0 = alpha * acc[i][0] + bv.x;
        float r1 = alpha * acc[i][1] + bv.y;
        float r2 = alpha * acc[i][2] + bv.z;
        float r3 = alpha * acc[i][3] + bv.w;
        if (GELU) { r0 = gelu_tanh(r0); r1 = gelu_tanh(r1); r2 = gelu_tanh(r2); r3 = gelu_tanh(r3); }
        if (RESID) {
            float4 old = *cp;
            r0 += old.x; r1 += old.y; r2 += old.z; r3 += old.w;
        }
        *cp = make_float4(r0, r1, r2, r3);
    }
}

// ---------------- Masked row softmax over attn logits (in place) ----------------
// grid: (N, H, B); block 256; each thread handles 10 columns.
__global__ __launch_bounds__(256) void softmax_kernel(float* __restrict__ attn,
                                                      const int* __restrict__ mask) {
    int q = blockIdx.x, h = blockIdx.y, b = blockIdx.z;
    float* row = attn + (((size_t)(b * HEADS + h)) * NN + q) * NN;
    int t = threadIdx.x;

    float v[10];
    bool ok[10];
    float lmax = -INFINITY;
#pragma unroll
    for (int i = 0; i < 10; ++i) {
        int col = t + i * 256;
        int cls = col >> 9;                       // col / 512
        ok[i] = (cls >= NCLS) || (mask[b * NCLS + cls] != 0);
        v[i] = row[col];
        if (ok[i]) lmax = fmaxf(lmax, v[i]);
    }
    // block reduce max
    __shared__ float red[4];
#pragma unroll
    for (int off = 32; off >= 1; off >>= 1) lmax = fmaxf(lmax, __shfl_xor(lmax, off, 64));
    if ((t & 63) == 0) red[t >> 6] = lmax;
    __syncthreads();
    float m = fmaxf(fmaxf(red[0], red[1]), fmaxf(red[2], red[3]));
    __syncthreads();

    float lsum = 0.f;
#pragma unroll
    for (int i = 0; i < 10; ++i) {
        if (ok[i]) { v[i] = __expf(v[i] - m); lsum += v[i]; }
    }
#pragma unroll
    for (int off = 32; off >= 1; off >>= 1) lsum += __shfl_xor(lsum, off, 64);
    if ((t & 63) == 0) red[t >> 6] = lsum;
    __syncthreads();
    float inv = 1.f / (red[0] + red[1] + red[2] + red[3]);

#pragma unroll
    for (int i = 0; i < 10; ++i) {
        int col = t + i * 256;
        row[col] = ok[i] ? v[i] * inv : 0.f;
    }
}

extern "C" void kernel_launch(void* const* d_in, const int* in_sizes, int n_in,
                              void* d_out, int out_size, void* d_ws, size_t ws_size,
                              hipStream_t stream) {
    const float* x_in   = (const float*)d_in[0];
    const int*   mask   = (const int*)d_in[1];
    const float* ln1_g  = (const float*)d_in[2];
    const float* ln1_b  = (const float*)d_in[3];
    const float* qkv_w  = (const float*)d_in[4];
    const float* proj_w = (const float*)d_in[5];
    const float* proj_b = (const float*)d_in[6];
    const float* ln2_g  = (const float*)d_in[7];
    const float* ln2_b  = (const float*)d_in[8];
    const float* ffn_w1 = (const float*)d_in[9];
    const float* ffn_b1 = (const float*)d_in[10];
    const float* ffn_w2 = (const float*)d_in[11];
    const float* ffn_b2 = (const float*)d_in[12];

    const size_t xsz = (size_t)BB * NN * DIM;          // 2,621,440
    float* xbuf     = (float*)d_out;                   // residual stream lives in d_out
    float* attn_all = (float*)d_out + xsz;             // [depth,B,H,N,N]

    float* h   = (float*)d_ws;                         // 5120*512
    float* qkv = h + xsz;                              // 5120*1536
    float* g   = qkv + (size_t)BB * NN * 3 * DIM;      // 5120*4096
    float* o   = h;                                    // alias: h dead after QKV gemm

    hipMemcpyAsync(xbuf, x_in, xsz * sizeof(float), hipMemcpyDeviceToDevice, stream);

    const int M = BB * NN;          // 5120
    dim3 blk(256);

    for (int j = 0; j < DEPTH; ++j) {
        // --- LN1: x -> h ---
        ln_kernel<<<dim3(M / 4), blk, 0, stream>>>(xbuf, ln1_g + j * DIM, ln1_b + j * DIM, h);

        // --- QKV: h @ qkv_w[j] -> qkv  (M=5120,N=1536,K=512) ---
        gemm_kernel<false, false, false><<<dim3(1536 / 64, M / 64, 1), blk, 0, stream>>>(
            h, DIM, 0, 0,
            qkv_w + (size_t)j * DIM * 3 * DIM, 3 * DIM, 0, 0,
            qkv, 3 * DIM, 0, 0,
            M, 3 * DIM, DIM, 1.f, nullptr, 1);

        // --- QK^T * scale -> attn logits  (per b,h: M=N=2560,K=64, B transposed) ---
        float* attn_j = attn_all + (size_t)j * BB * HEADS * NN * NN;
        gemm_kernel<true, false, false><<<dim3(NN / 64, NN / 64, BB * HEADS), blk, 0, stream>>>(
            qkv,        3 * DIM, (long long)NN * 3 * DIM, HD,       // Q
            qkv + DIM,  3 * DIM, (long long)NN * 3 * DIM, HD,       // K
            attn_j, NN, (long long)HEADS * NN * NN, (long long)NN * NN,
            NN, NN, HD, ATT_SCALE, nullptr, HEADS);

        // --- masked softmax in place ---
        softmax_kernel<<<dim3(NN, HEADS, BB), blk, 0, stream>>>(attn_j, mask);

        // --- PV: attn @ V -> o  (per b,h: M=2560,N=64,K=2560) ---
        gemm_kernel<false, false, false><<<dim3(1, NN / 64, BB * HEADS), blk, 0, stream>>>(
            attn_j, NN, (long long)HEADS * NN * NN, (long long)NN * NN,
            qkv + 2 * DIM, 3 * DIM, (long long)NN * 3 * DIM, HD,    // V
            o, DIM, (long long)NN * DIM, HD,
            NN, HD, NN, 1.f, nullptr, HEADS);

        // --- proj: x += o @ proj_w[j] + proj_b[j]  (M=5120,N=512,K=512) ---
        gemm_kernel<false, false, true><<<dim3(DIM / 64, M / 64, 1), blk, 0, stream>>>(
            o, DIM, 0, 0,
            proj_w + (size_t)j * DIM * DIM, DIM, 0, 0,
            xbuf, DIM, 0, 0,
            M, DIM, DIM, 1.f, proj_b + j * DIM, 1);

        // --- LN2: x -> h ---
        ln_kernel<<<dim3(M / 4), blk, 0, stream>>>(xbuf, ln2_g + j * DIM, ln2_b + j * DIM, h);

        // --- FFN1: gelu(h @ w1 + b1) -> g  (M=5120,N=4096,K=512) ---
        gemm_kernel<false, true, false><<<dim3(4096 / 64, M / 64, 1), blk, 0, stream>>>(
            h, DIM, 0, 0,
            ffn_w1 + (size_t)j * DIM * 4096, 4096, 0, 0,
            g, 4096, 0, 0,
            M, 4096, DIM, 1.f, ffn_b1 + (size_t)j * 4096, 1);

        // --- FFN2: x += g @ w2 + b2  (M=5120,N=512,K=4096) ---
        gemm_kernel<false, false, true><<<dim3(DIM / 64, M / 64, 1), blk, 0, stream>>>(
            g, 4096, 0, 0,
            ffn_w2 + (size_t)j * 4096 * DIM, DIM, 0, 0,
            xbuf, DIM, 0, 0,
            M, DIM, 4096, 1.f, ffn_b2 + j * DIM, 1);
    }
}